// Round 17
// baseline (497.746 us; speedup 1.0000x reference)
//
#include <hip/hip_runtime.h>
#include <hip/hip_fp16.h>
#include <math.h>

#define BSZ   4
#define SEQL  2048
#define DIN   40
#define DM    128
#define DI    256
#define DS    16
#define NL    4
#define NHEAD 4
#define DHEAD 32
#define KLM   100
#define NC    128       // chunks per sequence
#define TC    16        // SEQL / NC
#define NROWS 8         // rows per pre block
#define EROWS 16

typedef _Float16 v2h __attribute__((ext_vector_type(2)));

__device__ __forceinline__ float rcp_(float x){ return __builtin_amdgcn_rcpf(x); }
__device__ __forceinline__ float sigmoidf_(float x){ return rcp_(1.0f + __expf(-x)); }
__device__ __forceinline__ float siluf_(float x){ return x*rcp_(1.0f + __expf(-x)); }
__device__ __forceinline__ float softplusf_(float x){ return fmaxf(x,0.0f) + __logf(1.0f + __expf(-fabsf(x))); }
__device__ __forceinline__ float fdot2_(__half2 a, __half2 b, float c){
  return __builtin_amdgcn_fdot2(*(v2h*)&a, *(v2h*)&b, c, false);
}

__device__ __forceinline__ void load8(const float* p, float* r){
  const float4* q = (const float4*)p;
  float4 a=q[0], b=q[1];
  r[0]=a.x;r[1]=a.y;r[2]=a.z;r[3]=a.w; r[4]=b.x;r[5]=b.y;r[6]=b.z;r[7]=b.w;
}
__device__ __forceinline__ void store8(float* p, const float* r){
  float4* q = (float4*)p;
  q[0]=make_float4(r[0],r[1],r[2],r[3]);  q[1]=make_float4(r[4],r[5],r[6],r[7]);
}
__device__ __forceinline__ void load16(const float* p, float* r){
  load8(p, r); load8(p+8, r+8);
}
__device__ __forceinline__ void store16(float* p, const float* r){
  store8(p, r); store8(p+8, r+8);
}

// ---------------- one-time weight conversion: Wi, Wo -> k-pair-packed half2 ----------------
__global__ __launch_bounds__(256) void convw_kernel(
    const float* __restrict__ inW, const float* __restrict__ outW,
    __half* __restrict__ Wip, __half* __restrict__ Wop)
{
  const int i = blockIdx.x*256 + threadIdx.x;
  if (i < NL*DM*2*DI){
    const int col = i & 511;
    const int klin = i >> 9;
    const int l = klin >> 7, k = klin & 127;
    Wip[(((size_t)(l*64 + (k>>1))*512 + col) << 1) + (k & 1)] = __float2half_rn(inW[i]);
  }
  if (i < NL*DI*DM){
    const int c = i & (DM-1);
    const int klin = i >> 7;
    const int l = klin >> 8, k = klin & 255;
    Wop[(((size_t)(l*128 + (k>>1))*DM + c) << 1) + (k & 1)] = __float2half_rn(outW[i]);
  }
}

// ---------------- topk over hawkes weights only ----------------
__global__ __launch_bounds__(256) void topk_kernel(
    const float* __restrict__ hw, int* __restrict__ idxl_g)
{
  __shared__ int redcnt[2][4];
  __shared__ int eqc[8][4], gtc[8][4];

  const int b = blockIdx.x;
  const int t = threadIdx.x;
  const int lane = t & 63, w = t >> 6;

  const float* hwp = hw + (size_t)b*SEQL;
  unsigned vb[8];
  #pragma unroll
  for (int q=0;q<8;q++) vb[q] = __float_as_uint(hwp[q*256 + t]);

  unsigned kth = 0u;
  for (int bit=31; bit>=0; --bit){
    const unsigned cand = kth | (1u << bit);
    int c0 = 0;
    #pragma unroll
    for (int q=0;q<8;q++) c0 += __popcll(__ballot(vb[q] >= cand));
    const int par = bit & 1;
    if (lane == 0) redcnt[par][w] = c0;
    __syncthreads();
    const int tot = redcnt[par][0]+redcnt[par][1]+redcnt[par][2]+redcnt[par][3];
    if (tot >= KLM) kth = cand;
  }

  unsigned long long beq[8], bgt[8];
  #pragma unroll
  for (int q=0;q<8;q++){
    beq[q] = __ballot(vb[q] == kth);
    bgt[q] = __ballot(vb[q] >  kth);
  }
  if (lane == 0){
    #pragma unroll
    for (int q=0;q<8;q++){ eqc[q][w] = __popcll(beq[q]); gtc[q][w] = __popcll(bgt[q]); }
  }
  __syncthreads();
  {
    int gtTot = 0;
    #pragma unroll
    for (int q=0;q<8;q++) gtTot += gtc[q][0]+gtc[q][1]+gtc[q][2]+gtc[q][3];
    const int need_eq = KLM - gtTot;
    const unsigned long long lmask = (lane==0) ? 0ull : ((~0ull) >> (64-lane));
    int eqPfx = 0, gtPfx = 0;
    #pragma unroll
    for (int q=0;q<8;q++){
      int eqWP = 0, gtWP = 0;
      for (int w2=0; w2<w; ++w2){ eqWP += eqc[q][w2]; gtWP += gtc[q][w2]; }
      const int eqBefore = eqPfx + eqWP + __popcll(beq[q] & lmask);
      const int gtBefore = gtPfx + gtWP + __popcll(bgt[q] & lmask);
      if (vb[q] > kth){
        const int pos = gtBefore + min(eqBefore, need_eq);
        if (pos < KLM) idxl_g[b*KLM + pos] = q*256 + t;
      } else if (vb[q] == kth && eqBefore < need_eq){
        const int pos = gtBefore + eqBefore;
        if (pos < KLM) idxl_g[b*KLM + pos] = q*256 + t;
      }
      eqPfx += eqc[q][0]+eqc[q][1]+eqc[q][2]+eqc[q][3];
      gtPfx += gtc[q][0]+gtc[q][1]+gtc[q][2]+gtc[q][3];
    }
  }
}

// ---------------- embed ----------------
__global__ __launch_bounds__(256) void embed_kernel(
    const float* __restrict__ x, const float* __restrict__ hw,
    const float* __restrict__ eW, const float* __restrict__ eb,
    const float* __restrict__ sW, const float* __restrict__ sb,
    float* __restrict__ hb, float* __restrict__ sk)
{
  __shared__ float xr[EROWS][DIN];
  const int t = threadIdx.x;
  const size_t R0 = (size_t)blockIdx.x * EROWS;
  for (int e=t; e<EROWS*DIN; e+=256) ((float*)xr)[e] = x[R0*DIN + e];
  __syncthreads();
  const int c = t & (DM-1), g = t >> 7;
  float ae[8], as[8];
  #pragma unroll
  for (int j=0;j<8;j++){ ae[j]=0.0f; as[j]=0.0f; }
  for (int k=0;k<DIN;k++){
    const float we  = eW[(size_t)k*DM + c];
    const float ws_ = sW[(size_t)k*DM + c];
    #pragma unroll
    for (int j=0;j<8;j++){
      const float xv = xr[g*8+j][k];
      ae[j] = fmaf(xv, we, ae[j]);
      as[j] = fmaf(xv, ws_, as[j]);
    }
  }
  const float ebv = eb[c], sbv = sb[c];
  #pragma unroll
  for (int j=0;j<8;j++){
    const size_t R = R0 + g*8 + j;
    const float w = hw[R];
    hb[R*DM + c] = (ae[j]+ebv)*w;
    sk[R*DM + c] = (as[j]+sbv)*w;
  }
}

// ---------------- fused pre: LN -> in_proj(fdot2) -> silu -> x_proj -> B/C/dt/lam ----------------
__global__ __launch_bounds__(256) void pre_kernel(
    const float* __restrict__ hb,
    const __half* __restrict__ Wip, const float* __restrict__ Wx,
    const float* __restrict__ Wdt, const float* __restrict__ bdt,
    const float* __restrict__ Bb, const float* __restrict__ Cb,
    const float* __restrict__ Bnw, const float* __restrict__ Cnw,
    const float* __restrict__ lnw, const float* __restrict__ lnb,
    __half* __restrict__ xph, __half* __restrict__ zsh,
    float* __restrict__ dtin, float* __restrict__ Shalf,
    float* __restrict__ Bmb, float* __restrict__ Cmb,
    float* __restrict__ lamb, float* __restrict__ mdtb)
{
  __shared__ __half2 xinh[NROWS][64+2];
  __shared__ float xps[NROWS][DI+4];
  __shared__ float spl[NROWS][40];
  __shared__ float pr[NROWS][4];

  const int t = threadIdx.x;
  const size_t R0 = (size_t)blockIdx.x * NROWS;

  { // LayerNorm: 32 threads per row; write half2 pairs
    const int r = t >> 5, j = t & 31;
    const float4 v = ((const float4*)(hb + (R0 + r)*DM))[j];
    float s = v.x+v.y+v.z+v.w;
    #pragma unroll
    for (int o=16;o>0;o>>=1) s += __shfl_xor(s,o,32);
    const float m = s*(1.0f/DM);
    const float dx=v.x-m, dy=v.y-m, dz=v.z-m, dw=v.w-m;
    float ss = dx*dx+dy*dy+dz*dz+dw*dw;
    #pragma unroll
    for (int o=16;o>0;o>>=1) ss += __shfl_xor(ss,o,32);
    const float inv = 1.0f/sqrtf(ss*(1.0f/DM) + 1e-5f);
    const int c = j*4;
    const float v0 = dx*inv*lnw[c+0] + lnb[c+0];
    const float v1 = dy*inv*lnw[c+1] + lnb[c+1];
    const float v2 = dz*inv*lnw[c+2] + lnb[c+2];
    const float v3 = dw*inv*lnw[c+3] + lnb[c+3];
    xinh[r][2*j]   = __halves2half2(__float2half_rn(v0), __float2half_rn(v1));
    xinh[r][2*j+1] = __halves2half2(__float2half_rn(v2), __float2half_rn(v3));
  }
  __syncthreads();

  { // xz = xin @ Wi via fdot2; thread t owns cols 2t,2t+1
    float2 a[NROWS];
    #pragma unroll
    for (int r=0;r<NROWS;r++){ a[r].x=0.0f; a[r].y=0.0f; }
    const __half2* Wc = (const __half2*)Wip + 2*t;
    #pragma unroll 4
    for (int p=0;p<64;p++){
      const float2 wv = *(const float2*)&Wc[(size_t)p*512];
      const __half2 w0 = *(const __half2*)&wv.x;
      const __half2 w1 = *(const __half2*)&wv.y;
      #pragma unroll
      for (int r=0;r<NROWS;r++){
        const __half2 xv = xinh[r][p];
        a[r].x = fdot2_(xv, w0, a[r].x);
        a[r].y = fdot2_(xv, w1, a[r].y);
      }
    }
    if (t < 128){
      #pragma unroll
      for (int r=0;r<NROWS;r++){
        const float sx = siluf_(a[r].x), sy = siluf_(a[r].y);
        xps[r][2*t] = sx; xps[r][2*t+1] = sy;
        *(__half2*)&xph[(R0+r)*DI + 2*t] =
            __halves2half2(__float2half_rn(sx), __float2half_rn(sy));
      }
    } else {
      const int zc = 2*t - 2*DI + DI;
      #pragma unroll
      for (int r=0;r<NROWS;r++){
        const float sx = siluf_(a[r].x), sy = siluf_(a[r].y);
        *(__half2*)&zsh[(R0+r)*DI + zc] =
            __halves2half2(__float2half_rn(sx), __float2half_rn(sy));
      }
    }
  }
  __syncthreads();

  // sp = xp @ Wx.  136 tasks = 8 rows x 17 col-pairs
  if (t < 136){
    const int r = t & 7, op = t >> 3;
    float ax=0.0f, ay=0.0f;
    for (int k=0;k<DI;k+=4){
      const float4 xv = *(const float4*)&xps[r][k];
      const float2 w0 = *(const float2*)&Wx[(size_t)(k+0)*34 + 2*op];
      const float2 w1 = *(const float2*)&Wx[(size_t)(k+1)*34 + 2*op];
      const float2 w2 = *(const float2*)&Wx[(size_t)(k+2)*34 + 2*op];
      const float2 w3 = *(const float2*)&Wx[(size_t)(k+3)*34 + 2*op];
      ax = fmaf(xv.x,w0.x,ax); ay = fmaf(xv.x,w0.y,ay);
      ax = fmaf(xv.y,w1.x,ax); ay = fmaf(xv.y,w1.y,ay);
      ax = fmaf(xv.z,w2.x,ax); ay = fmaf(xv.z,w2.y,ay);
      ax = fmaf(xv.w,w3.x,ax); ay = fmaf(xv.w,w3.y,ay);
    }
    spl[r][2*op] = ax; spl[r][2*op+1] = ay;
  }
  __syncthreads();

  { // B/C rms-norm: 256 tasks = 2 halves x 8 rows x 16 states
    const int half = t >> 7;
    const int r2 = (t >> 4) & 7, s2 = t & 15;
    const float* bias = half ? Cb : Bb;
    const float* wn   = half ? Cnw : Bnw;
    const float v = spl[r2][half*DS + s2] + bias[s2];
    float ss = v*v;
    #pragma unroll
    for (int o=8;o>0;o>>=1) ss += __shfl_xor(ss,o,16);
    const float inv = 1.0f/sqrtf(ss*(1.0f/DS) + 1.1920929e-07f);
    (half ? Cmb : Bmb)[(R0+r2)*DS + s2] = v*inv*wn[s2];
  }

  { // dt: thread = d; loop 8 rows; accumulate half-chunk sum
    const int lane = t & 63, w = t >> 6;
    const float wdt = Wdt[t], bdtv = bdt[t];
    float Sd = 0.0f;
    #pragma unroll
    for (int r=0;r<NROWS;r++){
      const float dval = softplusf_(fmaf(spl[r][32], wdt, bdtv));
      Sd += dval;
      float s = dval;
      #pragma unroll
      for (int o=32;o>0;o>>=1) s += __shfl_xor(s,o,64);
      if (lane==0) pr[r][w] = s;
    }
    Shalf[(size_t)blockIdx.x * DI + t] = Sd;
    if (t < NROWS){
      lamb[R0+t] = sigmoidf_(spl[t][33]);
      dtin[R0+t] = spl[t][32];
    }
  }
  __syncthreads();
  if (t < NROWS)
    mdtb[R0+t] = (pr[t][0]+pr[t][1]+pr[t][2]+pr[t][3])*(1.0f/DI);
}

// ---------------- scan phase 1 (inline prefix + rotation sincos) ----------------
__global__ __launch_bounds__(512) void scan1_kernel(
    const __half* __restrict__ xph, const float* __restrict__ dtin,
    const float* __restrict__ Wdt, const float* __restrict__ bdt,
    const float* __restrict__ Bmb, const float* __restrict__ lamb,
    const float* __restrict__ mdtb, const float* __restrict__ rf,
    const float* __restrict__ Alog, float* __restrict__ hend)
{
  __shared__ float Bst[TC+1][DS];
  __shared__ float lst[TC];
  __shared__ float dsl[TC];
  __shared__ double fqs[8];
  __shared__ double wred[8];
  __shared__ double mloc[16];
  __shared__ __half xpl[TC+1][DI+8];
  const int t = threadIdx.x;
  const int d  = t >> 1;
  const int s0 = (t & 1) * 8;
  const int c = blockIdx.x & (NC-1);
  const int b = blockIdx.x >> 7;
  const size_t bL = (size_t)b*SEQL;
  const int t0 = c*TC;
  const int id = blockIdx.x*256 + d;

  if (t < 8){
    const double xfr = (double)rf[t];
    fqs[t] = fmax(xfr, 0.0) + log1p(exp(-fabs(xfr)));
  }
  { // prefix partial: sum mdtb[0..t0-1] in f64
    double s = 0.0;
    const int i0 = t*4;
    #pragma unroll
    for (int q=0;q<4;q++){
      const int idx = i0+q;
      s += (idx < t0) ? (double)mdtb[bL + idx] : 0.0;
    }
    #pragma unroll
    for (int o=32;o>0;o>>=1) s += __shfl_down(s,o,64);
    if ((t&63)==0) wred[t>>6] = s;
  }
  if (t >= 64 && t < 80) mloc[t-64] = (double)mdtb[bL + t0 + (t-64)];
  for (int e=t; e<(TC+1)*DS; e+=512){
    const int j = e >> 4, s = e & 15;
    const int trow = t0 - 1 + j;
    Bst[j][s] = (trow >= 0) ? Bmb[(bL + trow)*DS + s] : 0.0f;
  }
  for (int e=t; e<(TC+1)*DI; e+=512){
    const int j = e >> 8, dd = e & (DI-1);
    const int trow = t0 - 1 + j;
    xpl[j][dd] = (trow >= 0) ? xph[(bL + trow)*DI + dd] : __float2half_rn(0.0f);
  }
  if (t < TC){
    lst[t] = lamb[bL + t0 + t];
    dsl[t] = dtin[bL + t0 + t];
  }
  __syncthreads();
  if (t < 136){
    const int j = t >> 3, f = t & 7;
    const int trow = t0 - 1 + j;
    if (trow >= 0){
      double cs = wred[0]+wred[1]+wred[2]+wred[3]+wred[4]+wred[5]+wred[6]+wred[7];
      for (int i=0;i<j;i++) cs += mloc[i];
      const double ang = cs * fqs[f];
      const double red = ang - floor(ang*0.15915494309189535)*6.283185307179586;
      float sa, ca;
      __sincosf((float)red, &sa, &ca);
      const float e0 = Bst[j][2*f], o0 = Bst[j][2*f+1];
      Bst[j][2*f]   = e0*ca - o0*sa;
      Bst[j][2*f+1] = e0*sa + o0*ca;
    }
  }
  __syncthreads();

  float A[8];
  #pragma unroll
  for (int s=0;s<8;s++) A[s] = fminf(-__expf(Alog[d*DS + s0 + s]), -1e-4f);
  const float wdt = Wdt[d], bdtv = bdt[d];
  float h[8], Bprev[8];
  #pragma unroll
  for (int s=0;s<8;s++) h[s]=0.0f;
  float xpm1;
  int tstart;
  if (t0 > 0){
    #pragma unroll
    for (int s=0;s<8;s++) Bprev[s] = Bst[0][s0+s];
    xpm1 = __half2float(xpl[0][d]);
    tstart = 0;
  } else {
    const float dtv = softplusf_(fmaf(dsl[0], wdt, bdtv));
    const float xpv = __half2float(xpl[1][d]);
    #pragma unroll
    for (int s=0;s<8;s++){
      h[s] = dtv*(Bst[1][s0+s]*xpv);
      Bprev[s] = Bst[1][s0+s];
    }
    xpm1 = xpv;
    tstart = 1;
  }
  for (int j=tstart; j<TC; ++j){
    const float dtv = softplusf_(fmaf(dsl[j], wdt, bdtv));
    const float xpv = __half2float(xpl[j+1][d]);
    const float lamv = lst[j];
    const float dl = dtv*lamv;
    const float dml = dtv - dl;
    #pragma unroll
    for (int s=0;s<8;s++){
      const float a = __expf(A[s]*dtv);
      const float Bc = Bst[j+1][s0+s];
      const float u = fmaf(dml*a, Bprev[s]*xpm1, dl*(Bc*xpv));
      h[s] = fmaf(a, h[s], u);
      Bprev[s] = Bc;
    }
    xpm1 = xpv;
  }
  store8(hend + (size_t)id*DS + s0, h);
}

// ---------------- scan phase 2: parallel Kogge-Stone over chunks; P = exp(A*S) ----------------
__global__ __launch_bounds__(128) void scan2_kernel(
    float* __restrict__ hend, const float* __restrict__ Shalf,
    const float* __restrict__ Alog)
{
  __shared__ float hS[NC][DS+1];
  __shared__ float pS[NC][DS+1];
  const int c = threadIdx.x;
  const int d = blockIdx.x & (DI-1);
  const int b = blockIdx.x >> 8;
  const float S = Shalf[(size_t)(b*(SEQL/NROWS) + 2*c)*DI + d]
                + Shalf[(size_t)(b*(SEQL/NROWS) + 2*c + 1)*DI + d];
  float P[DS], h[DS];
  #pragma unroll
  for (int s=0;s<DS;s++){
    const float A = fminf(-__expf(Alog[d*DS+s]), -1e-4f);
    P[s] = __expf(A*S);
  }
  load16(hend + (((size_t)(b*NC + c))*DI + d)*DS, h);
  #pragma unroll
  for (int s=0;s<DS;s++){ hS[c][s]=h[s]; pS[c][s]=P[s]; }
  __syncthreads();
  for (int off=1; off<NC; off<<=1){
    float hn[DS], pn[DS];
    const int src = c - off;
    if (src >= 0){
      #pragma unroll
      for (int s=0;s<DS;s++){ hn[s]=hS[src][s]; pn[s]=pS[src][s]; }
    }
    __syncthreads();
    if (src >= 0){
      #pragma unroll
      for (int s=0;s<DS;s++){
        h[s] = fmaf(P[s], hn[s], h[s]);
        P[s] *= pn[s];
        hS[c][s] = h[s]; pS[c][s] = P[s];
      }
    }
    __syncthreads();
  }
  float o[DS];
  if (c == 0){
    #pragma unroll
    for (int s=0;s<DS;s++) o[s] = 0.0f;
  } else {
    #pragma unroll
    for (int s=0;s<DS;s++) o[s] = hS[c-1][s];
  }
  store16(hend + (((size_t)(b*NC + c))*DI + d)*DS, o);
}

// ---------------- scan phase 3 + fdot2 out_proj + residual (inline prefix) ----------------
__global__ __launch_bounds__(512) void scan3post_kernel(
    const __half* __restrict__ xph, const float* __restrict__ dtin,
    const float* __restrict__ Wdt, const float* __restrict__ bdt,
    const float* __restrict__ Bmb, const float* __restrict__ Cmb,
    const float* __restrict__ lamb, const __half* __restrict__ zsh,
    const float* __restrict__ mdtb, const float* __restrict__ rf,
    const float* __restrict__ Alog, const float* __restrict__ Dv,
    const float* __restrict__ Hin, const __half* __restrict__ Wop,
    float* __restrict__ hb)
{
  __shared__ float Bst[TC+1][DS];
  __shared__ float Cst[TC][DS];
  __shared__ float lst[TC];
  __shared__ float dsl[TC];
  __shared__ double fqs[8];
  __shared__ double wred[8];
  __shared__ double mloc[16];
  __shared__ __half xpl[TC+1][DI+8];
  __shared__ __half zsl[TC][DI+8];
  __shared__ __half ysh[TC][DI+8];
  __shared__ float red[TC][132];
  const int t = threadIdx.x;
  const int d  = t >> 1;
  const int sh = t & 1;
  const int s0 = sh * 8;
  const int c = blockIdx.x & (NC-1);
  const int b = blockIdx.x >> 7;
  const size_t bL = (size_t)b*SEQL;
  const int t0 = c*TC;
  const int id = blockIdx.x*256 + d;

  if (t < 8){
    const double xfr = (double)rf[t];
    fqs[t] = fmax(xfr, 0.0) + log1p(exp(-fabs(xfr)));
  }
  { // prefix partial
    double s = 0.0;
    const int i0 = t*4;
    #pragma unroll
    for (int q=0;q<4;q++){
      const int idx = i0+q;
      s += (idx < t0) ? (double)mdtb[bL + idx] : 0.0;
    }
    #pragma unroll
    for (int o=32;o>0;o>>=1) s += __shfl_down(s,o,64);
    if ((t&63)==0) wred[t>>6] = s;
  }
  if (t >= 64 && t < 80) mloc[t-64] = (double)mdtb[bL + t0 + (t-64)];
  for (int e=t; e<(TC+1)*DS; e+=512){
    const int j = e >> 4, s = e & 15;
    const int trow = t0 - 1 + j;
    Bst[j][s] = (trow >= 0) ? Bmb[(bL + trow)*DS + s] : 0.0f;
    if (j < TC) Cst[j][s] = Cmb[(bL + t0 + j)*DS + s];
  }
  for (int e=t; e<(TC+1)*DI; e+=512){
    const int j = e >> 8, dd = e & (DI-1);
    const int trow = t0 - 1 + j;
    xpl[j][dd] = (trow >= 0) ? xph[(bL + trow)*DI + dd] : __float2half_rn(0.0f);
    if (j < TC) zsl[j][dd] = zsh[(bL + t0 + j)*DI + dd];
  }
  if (t < TC){
    lst[t] = lamb[bL + t0 + t];
    dsl[t] = dtin[bL + t0 + t];
  }
  __syncthreads();
  if (t < 264){
    const double base = wred[0]+wred[1]+wred[2]+wred[3]+wred[4]+wred[5]+wred[6]+wred[7];
    if (t < 136){
      const int j = t >> 3, f = t & 7;
      const int trow = t0 - 1 + j;
      if (trow >= 0){
        double cs = base;
        for (int i=0;i<j;i++) cs += mloc[i];
        const double ang = cs * fqs[f];
        const double rd = ang - floor(ang*0.15915494309189535)*6.283185307179586;
        float sa, ca;
        __sincosf((float)rd, &sa, &ca);
        const float e0 = Bst[j][2*f], o0 = Bst[j][2*f+1];
        Bst[j][2*f]   = e0*ca - o0*sa;
        Bst[j][2*f+1] = e0*sa + o0*ca;
      }
    } else {
      const int e2 = t - 136;
      const int j = e2 >> 3, f = e2 & 7;
      double cs = base;
      for (int i=0;i<=j;i++) cs += mloc[i];
      const double ang = cs * fqs[f];
      const double rd = ang - floor(ang*0.15915494309189535)*6.283185307179586;
      float sa, ca;
      __sincosf((float)rd, &sa, &ca);
      const float e0 = Cst[j][2*f], o0 = Cst[j][2*f+1];
      Cst[j][2*f]   = e0*ca - o0*sa;
      Cst[j][2*f+1] = e0*sa + o0*ca;
    }
  }
  __syncthreads();

  float A[8];
  #pragma unroll
  for (int s=0;s<8;s++) A[s] = fminf(-__expf(Alog[d*DS + s0 + s]), -1e-4f);
  const float wdt = Wdt[d], bdtv = bdt[d];
  const float dvp = Dv[d];
  float h[8], Bprev[8];
  load8(Hin + (size_t)id*DS + s0, h);
  float xpm1;
  int tstart;
  if (t0 > 0){
    #pragma unroll
    for (int s=0;s<8;s++) Bprev[s] = Bst[0][s0+s];
    xpm1 = __half2float(xpl[0][d]);
    tstart = 0;
  } else {
    const float dtv = softplusf_(fmaf(dsl[0], wdt, bdtv));
    const float xpv = __half2float(xpl[1][d]);
    float y = 0.0f;
    #pragma unroll
    for (int s=0;s<8;s++){
      h[s] = dtv*(Bst[1][s0+s]*xpv);
      y = fmaf(h[s], Cst[0][s0+s], y);
      Bprev[s] = Bst[1][s0+s];
    }
    const float ytot = y + __shfl_xor(y, 1, 64);
    if (sh == 0) ysh[0][d] = __float2half_rn((ytot + xpv*dvp)*__half2float(zsl[0][d]));
    xpm1 = xpv;
    tstart = 1;
  }
  for (int j=tstart; j<TC; ++j){
    const float dtv = softplusf_(fmaf(dsl[j], wdt, bdtv));
    const float xpv = __half2float(xpl[j+1][d]);
    const float lamv = lst[j];
    const float dl = dtv*lamv;
    const float dml = dtv - dl;
    float y = 0.0f;
    #pragma unroll
    for (int s=0;s<8;s++){
      const float a = __expf(A[s]*dtv);
      const float Bc = Bst[j+1][s0+s];
      const float u = fmaf(dml*a, Bprev[s]*xpm1, dl*(Bc*xpv));
      h[s] = fmaf(a, h[s], u);
      y = fmaf(h[s], Cst[j][s0+s], y);
      Bprev[s] = Bc;
    }
    const float ytot = y + __shfl_xor(y, 1, 64);
    if (sh == 0) ysh[j][d] = __float2half_rn((ytot + xpv*dvp)*__half2float(zsl[j][d]));
    xpm1 = xpv;
  }
  __syncthreads();

  // ---- out_proj via fdot2 (k-pair packed Wo) + k-split + residual ----
  {
    const int cg2  = t & 31;          // col quad: cols 4cg2..4cg2+3
    const int ks2  = (t >> 5) & 1;    // k-seg low bit (within wave)
    const int rg   = (t >> 6) & 3;    // row quad
    const int ksHi = t >> 8;          // k-seg high bit (across waves)
    const int seg = ksHi*2 + ks2;
    const int k0p = seg*32;           // pair index base (32 pairs = 64 k)
    const int c0c = cg2*4;
    const __half2* Wp = (const __half2*)Wop;
    float acc[4][4];
    #pragma unroll
    for (int rr=0;rr<4;rr++){ acc[rr][0]=0.f; acc[rr][1]=0.f; acc[rr][2]=0.f; acc[rr][3]=0.f; }
    for (int kp=k0p; kp<k0p+32; ++kp){
      const float2 wv0 = *(const float2*)&Wp[(size_t)kp*DM + c0c];
      const float2 wv1 = *(const float2*)&Wp[(size_t)kp*DM + c0c + 2];
      const __half2 wc0 = *(const __half2*)&wv0.x;
      const __half2 wc1 = *(const __half2*)&wv0.y;
      const __half2 wc2 = *(const __half2*)&wv1.x;
      const __half2 wc3 = *(const __half2*)&wv1.y;
      #pragma unroll
      for (int rr=0;rr<4;rr++){
        const __half2 yv = *(const __half2*)&ysh[rg*4+rr][2*kp];
        acc[rr][0] = fdot2_(yv, wc0, acc[rr][0]);
        acc[rr][1] = fdot2_(yv, wc1, acc[rr][1]);
        acc[rr][2] = fdot2_(yv, wc2, acc[rr][2]);
        acc[rr][3] = fdot2_(yv, wc3, acc[rr][3]);
      }
    }
    // reduce ks2 within wave (lane +32)
    #pragma unroll
    for (int rr=0;rr<4;rr++){
      #pragma unroll
      for (int cc=0;cc<4;cc++) acc[rr][cc] += __shfl_down(acc[rr][cc], 32, 64);
    }
    __syncthreads();
    const int lane = t & 63;
    if (ksHi == 1 && lane < 32){
      #pragma unroll
      for (int rr=0;rr<4;rr++)
        *(float4*)&red[rg*4+rr][c0c] = make_float4(acc[rr][0],acc[rr][1],acc[rr][2],acc[rr][3]);
    }
    __syncthreads();
    if (ksHi == 0 && lane < 32){
      #pragma unroll
      for (int rr=0;rr<4;rr++){
        const float4 rv = *(const float4*)&red[rg*4+rr][c0c];
        const size_t row = bL + t0 + rg*4 + rr;
        float4 hv = *(const float4*)&hb[row*DM + c0c];
        hv.x += acc[rr][0] + rv.x; hv.y += acc[rr][1] + rv.y;
        hv.z += acc[rr][2] + rv.z; hv.w += acc[rr][3] + rv.w;
        *(float4*)&hb[row*DM + c0c] = hv;
      }
    }
  }
}

// ---------------- per-(b,head) attention with inline final-LN ----------------
__global__ __launch_bounds__(256) void attnmid_kernel(
    const float* __restrict__ hb, const float* __restrict__ sk,
    const int* __restrict__ idxl_g,
    const float* __restrict__ fnw, const float* __restrict__ fnb,
    const float* __restrict__ WQ, const float* __restrict__ bQ,
    const float* __restrict__ WK, const float* __restrict__ bK,
    const float* __restrict__ WV, const float* __restrict__ bV,
    float* __restrict__ attnog)
{
  __shared__ float kv[KLM][DM+4];
  __shared__ float mo[DM];
  __shared__ float Qs[DHEAD];
  __shared__ float qk[DM];
  __shared__ float sc[KLM];
  __shared__ float pbar[DM];
  __shared__ float bterm_s;
  const int t = threadIdx.x;
  const int b = blockIdx.x >> 2, hh = blockIdx.x & 3;
  const int c0 = hh*DHEAD;

  if (t < 64){
    const float* hr = hb + ((size_t)b*SEQL + (SEQL-1))*DM;
    const float v0 = hr[t], v1 = hr[t+64];
    float s = v0+v1;
    #pragma unroll
    for (int o=32;o>0;o>>=1) s += __shfl_xor(s,o,64);
    const float m = s*(1.0f/DM);
    const float d0=v0-m, d1=v1-m;
    float ss = d0*d0 + d1*d1;
    #pragma unroll
    for (int o=32;o>0;o>>=1) ss += __shfl_xor(ss,o,64);
    const float inv = 1.0f/sqrtf(ss*(1.0f/DM) + 1e-5f);
    mo[t]    = d0*inv*fnw[t]    + fnb[t];
    mo[t+64] = d1*inv*fnw[t+64] + fnb[t+64];
  }
  for (int e=t; e<KLM*DM; e+=256){
    const int j = e >> 7, cc = e & (DM-1);
    kv[j][cc] = sk[((size_t)b*SEQL + idxl_g[b*KLM + j])*DM + cc];
  }
  __syncthreads();
  if (t < DHEAD){
    float a = bQ[c0+t];
    #pragma unroll 4
    for (int k=0;k<DM;k++) a = fmaf(mo[k], WQ[(size_t)k*DM + c0+t], a);
    Qs[t] = a;
  }
  __syncthreads();
  if (t < DM){
    float a = 0.0f;
    #pragma unroll
    for (int cc=0; cc<DHEAD; cc++) a = fmaf(WK[(size_t)t*DM + c0 + cc], Qs[cc], a);
    qk[t] = a;
  } else if (t == DM){
    float a = 0.0f;
    for (int cc=0; cc<DHEAD; cc++) a += bK[c0+cc]*Qs[cc];
    bterm_s = a;
  }
  __syncthreads();
  if (t < KLM){
    float a = bterm_s;
    for (int m=0;m<DM;m+=4){
      const float4 kvv = *(const float4*)&kv[t][m];
      const float4 qv  = *(const float4*)&qk[m];
      a = fmaf(kvv.x,qv.x,a); a = fmaf(kvv.y,qv.y,a);
      a = fmaf(kvv.z,qv.z,a); a = fmaf(kvv.w,qv.w,a);
    }
    sc[t] = a*0.17677669529663687f;
  }
  __syncthreads();
  if (t < 64){
    const int lane = t;
    const float v0 = (lane < KLM) ? sc[lane] : -3.0e38f;
    const float v1 = (lane+64 < KLM) ? sc[lane+64] : -3.0e38f;
    float mx = fmaxf(v0, v1);
    #pragma unroll
    for (int o2=32;o2>0;o2>>=1) mx = fmaxf(mx, __shfl_xor(mx,o2,64));
    const float e0 = (lane < KLM) ? __expf(v0-mx) : 0.0f;
    const float e1 = (lane+64 < KLM) ? __expf(v1-mx) : 0.0f;
    float sm = e0+e1;
    #pragma unroll
    for (int o2=32;o2>0;o2>>=1) sm += __shfl_xor(sm,o2,64);
    const float inv2 = rcp_(sm);
    if (lane < KLM) sc[lane] = e0*inv2;
    if (lane+64 < KLM) sc[lane+64] = e1*inv2;
  }
  __syncthreads();
  if (t < DM){
    float a = 0.0f;
    #pragma unroll 4
    for (int j=0;j<KLM;j++) a = fmaf(sc[j], kv[j][t], a);
    pbar[t] = a;
  }
  __syncthreads();
  if (t < DHEAD){
    const int cc = c0 + t;
    float a = bV[cc];
    #pragma unroll 4
    for (int m=0;m<DM;m++) a = fmaf(pbar[m], WV[(size_t)m*DM + cc], a);
    attnog[b*DM + cc] = a;
  }
}

// ---------------- output projection ----------------
__global__ __launch_bounds__(128) void attnout_kernel(
    const float* __restrict__ attnog, const float* __restrict__ WO,
    const float* __restrict__ bO, float* __restrict__ outp)
{
  __shared__ float ao[DM];
  const int b = blockIdx.x, t = threadIdx.x;
  ao[t] = attnog[b*DM + t];
  __syncthreads();
  float a = bO[t];
  #pragma unroll 4
  for (int c2=0;c2<DM;c2++) a = fmaf(ao[c2], WO[(size_t)c2*DM + t], a);
  outp[(size_t)b*DM + t] = a;
}

extern "C" void kernel_launch(void* const* d_in, const int* in_sizes, int n_in,
                              void* d_out, int out_size, void* d_ws, size_t ws_size,
                              hipStream_t stream)
{
  (void)in_sizes; (void)n_in; (void)out_size; (void)ws_size;
  const float* x    = (const float*)d_in[0];
  const float* hw   = (const float*)d_in[1];
  const float* embW = (const float*)d_in[2];
  const float* embB = (const float*)d_in[3];
  const float* skW  = (const float*)d_in[4];
  const float* skB  = (const float*)d_in[5];
  const float* inW  = (const float*)d_in[6];
  const float* xpW  = (const float*)d_in[7];
  const float* dtW  = (const float*)d_in[8];
  const float* dtB  = (const float*)d_in[9];
  const float* Alog = (const float*)d_in[10];
  const float* Bb   = (const float*)d_in[11];
  const float* Cb   = (const float*)d_in[12];
  const float* Bnw  = (const float*)d_in[13];
  const float* Cnw  = (const float*)d_in[14];
  const float* rf   = (const float*)d_in[15];
  const float* Dpar = (const float*)d_in[16];
  const float* outW = (const float*)d_in[17];
  const float* lnW  = (const float*)d_in[18];
  const float* lnB  = (const float*)d_in[19];
  const float* fnW  = (const float*)d_in[20];
  const float* fnB  = (const float*)d_in[21];
  const float* WQ = (const float*)d_in[22]; const float* bQ = (const float*)d_in[23];
  const float* WK = (const float*)d_in[24]; const float* bK = (const float*)d_in[25];
  const float* WV = (const float*)d_in[26]; const float* bV = (const float*)d_in[27];
  const float* WO = (const float*)d_in[28]; const float* bO = (const float*)d_in[29];

  float* ws = (float*)d_ws;
  size_t off = 0;
  float* hb    = ws + off; off += (size_t)BSZ*SEQL*DM;
  float* sk    = ws + off; off += (size_t)BSZ*SEQL*DM;
  __half* xph  = (__half*)(ws + off); off += (size_t)BSZ*SEQL*DI/2;
  __half* zsh  = (__half*)(ws + off); off += (size_t)BSZ*SEQL*DI/2;
  float* Bmb   = ws + off; off += (size_t)BSZ*SEQL*DS;
  float* Cmb   = ws + off; off += (size_t)BSZ*SEQL*DS;
  float* lamb  = ws + off; off += (size_t)BSZ*SEQL;
  float* mdtb  = ws + off; off += (size_t)BSZ*SEQL;
  float* dtin  = ws + off; off += (size_t)BSZ*SEQL;
  float* Shalf = ws + off; off += (size_t)BSZ*(SEQL/NROWS)*DI;
  float* hend  = ws + off; off += (size_t)BSZ*NC*DI*DS;
  int* idxl_g  = (int*)(ws + off); off += (size_t)BSZ*KLM;
  float* attnog= ws + off; off += (size_t)BSZ*DM;
  __half* Wip  = (__half*)(ws + off); off += (size_t)NL*DM*2*DI/2;
  __half* Wop  = (__half*)(ws + off); off += (size_t)NL*DI*DM/2;

  convw_kernel<<<(NL*DM*2*DI + 255)/256, 256, 0, stream>>>(inW, outW, Wip, Wop);
  topk_kernel<<<BSZ, 256, 0, stream>>>(hw, idxl_g);
  embed_kernel<<<BSZ*SEQL/EROWS, 256, 0, stream>>>(x, hw, embW, embB, skW, skB, hb, sk);

  for (int i=0;i<NL;i++){
    pre_kernel<<<BSZ*SEQL/NROWS, 256, 0, stream>>>(hb,
        Wip + (size_t)i*DM*2*DI, xpW + (size_t)i*DI*34,
        dtW + (size_t)i*DI, dtB + (size_t)i*DI,
        Bb + i*DS, Cb + i*DS, Bnw + i*DS, Cnw + i*DS,
        lnW + i*DM, lnB + i*DM,
        xph, zsh, dtin, Shalf, Bmb, Cmb, lamb, mdtb);
    scan1_kernel<<<BSZ*NC, 512, 0, stream>>>(xph, dtin,
        dtW + (size_t)i*DI, dtB + (size_t)i*DI,
        Bmb, lamb, mdtb, rf + i*8, Alog + (size_t)i*DI*DS, hend);
    scan2_kernel<<<BSZ*DI, 128, 0, stream>>>(hend, Shalf, Alog + (size_t)i*DI*DS);
    scan3post_kernel<<<BSZ*NC, 512, 0, stream>>>(xph, dtin,
        dtW + (size_t)i*DI, dtB + (size_t)i*DI,
        Bmb, Cmb, lamb, zsh, mdtb, rf + i*8,
        Alog + (size_t)i*DI*DS, Dpar + (size_t)i*DI, hend,
        Wop + (size_t)i*DI*DM, hb);
  }

  attnmid_kernel<<<BSZ*NHEAD, 256, 0, stream>>>(hb, sk, idxl_g, fnW, fnB,
      WQ, bQ, WK, bK, WV, bV, attnog);
  attnout_kernel<<<BSZ, 128, 0, stream>>>(attnog, WO, bO, (float*)d_out);
}

// Round 18
// 473.565 us; speedup vs baseline: 1.0511x; 1.0511x over previous
//
#include <hip/hip_runtime.h>
#include <hip/hip_fp16.h>
#include <math.h>

#define BSZ   4
#define SEQL  2048
#define DIN   40
#define DM    128
#define DI    256
#define DS    16
#define NL    4
#define NHEAD 4
#define DHEAD 32
#define KLM   100
#define NC    128       // chunks per sequence
#define TC    16        // SEQL / NC
#define NROWS 8         // rows per pre block
#define EROWS 16

typedef _Float16 v2h __attribute__((ext_vector_type(2)));

__device__ __forceinline__ float rcp_(float x){ return __builtin_amdgcn_rcpf(x); }
__device__ __forceinline__ float sigmoidf_(float x){ return rcp_(1.0f + __expf(-x)); }
__device__ __forceinline__ float siluf_(float x){ return x*rcp_(1.0f + __expf(-x)); }
__device__ __forceinline__ float softplusf_(float x){ return fmaxf(x,0.0f) + __logf(1.0f + __expf(-fabsf(x))); }
__device__ __forceinline__ float fdot2_(__half2 a, __half2 b, float c){
  return __builtin_amdgcn_fdot2(*(v2h*)&a, *(v2h*)&b, c, false);
}

__device__ __forceinline__ void load8(const float* p, float* r){
  const float4* q = (const float4*)p;
  float4 a=q[0], b=q[1];
  r[0]=a.x;r[1]=a.y;r[2]=a.z;r[3]=a.w; r[4]=b.x;r[5]=b.y;r[6]=b.z;r[7]=b.w;
}
__device__ __forceinline__ void store8(float* p, const float* r){
  float4* q = (float4*)p;
  q[0]=make_float4(r[0],r[1],r[2],r[3]);  q[1]=make_float4(r[4],r[5],r[6],r[7]);
}
__device__ __forceinline__ void load16(const float* p, float* r){
  load8(p, r); load8(p+8, r+8);
}
__device__ __forceinline__ void store16(float* p, const float* r){
  store8(p, r); store8(p+8, r+8);
}

// ---------------- prologue: blocks 0..511 embed | 512..515 topk | 516+ convw ----------------
__global__ __launch_bounds__(256) void prologue_kernel(
    const float* __restrict__ x, const float* __restrict__ hw,
    const float* __restrict__ eW, const float* __restrict__ eb,
    const float* __restrict__ sW, const float* __restrict__ sb,
    float* __restrict__ hb, float* __restrict__ sk,
    const float* __restrict__ inW, const float* __restrict__ outW,
    __half* __restrict__ Wip, __half* __restrict__ Wop,
    int* __restrict__ idxl_g)
{
  __shared__ float xr[EROWS][DIN];
  __shared__ int redcnt[2][4];
  __shared__ int eqc[8][4], gtc[8][4];

  const int blk = blockIdx.x;
  const int t = threadIdx.x;

  if (blk < 512){
    // ---- embed ----
    const size_t R0 = (size_t)blk * EROWS;
    for (int e=t; e<EROWS*DIN; e+=256) ((float*)xr)[e] = x[R0*DIN + e];
    __syncthreads();
    const int c = t & (DM-1), g = t >> 7;
    float ae[8], as[8];
    #pragma unroll
    for (int j=0;j<8;j++){ ae[j]=0.0f; as[j]=0.0f; }
    for (int k=0;k<DIN;k++){
      const float we  = eW[(size_t)k*DM + c];
      const float ws_ = sW[(size_t)k*DM + c];
      #pragma unroll
      for (int j=0;j<8;j++){
        const float xv = xr[g*8+j][k];
        ae[j] = fmaf(xv, we, ae[j]);
        as[j] = fmaf(xv, ws_, as[j]);
      }
    }
    const float ebv = eb[c], sbv = sb[c];
    #pragma unroll
    for (int j=0;j<8;j++){
      const size_t R = R0 + g*8 + j;
      const float w = hw[R];
      hb[R*DM + c] = (ae[j]+ebv)*w;
      sk[R*DM + c] = (as[j]+sbv)*w;
    }
  } else if (blk < 516){
    // ---- topk for batch b ----
    const int b = blk - 512;
    const int lane = t & 63, w = t >> 6;
    const float* hwp = hw + (size_t)b*SEQL;
    unsigned vb[8];
    #pragma unroll
    for (int q=0;q<8;q++) vb[q] = __float_as_uint(hwp[q*256 + t]);
    unsigned kth = 0u;
    for (int bit=31; bit>=0; --bit){
      const unsigned cand = kth | (1u << bit);
      int c0 = 0;
      #pragma unroll
      for (int q=0;q<8;q++) c0 += __popcll(__ballot(vb[q] >= cand));
      const int par = bit & 1;
      if (lane == 0) redcnt[par][w] = c0;
      __syncthreads();
      const int tot = redcnt[par][0]+redcnt[par][1]+redcnt[par][2]+redcnt[par][3];
      if (tot >= KLM) kth = cand;
    }
    unsigned long long beq[8], bgt[8];
    #pragma unroll
    for (int q=0;q<8;q++){
      beq[q] = __ballot(vb[q] == kth);
      bgt[q] = __ballot(vb[q] >  kth);
    }
    if (lane == 0){
      #pragma unroll
      for (int q=0;q<8;q++){ eqc[q][w] = __popcll(beq[q]); gtc[q][w] = __popcll(bgt[q]); }
    }
    __syncthreads();
    int gtTot = 0;
    #pragma unroll
    for (int q=0;q<8;q++) gtTot += gtc[q][0]+gtc[q][1]+gtc[q][2]+gtc[q][3];
    const int need_eq = KLM - gtTot;
    const unsigned long long lmask = (lane==0) ? 0ull : ((~0ull) >> (64-lane));
    int eqPfx = 0, gtPfx = 0;
    #pragma unroll
    for (int q=0;q<8;q++){
      int eqWP = 0, gtWP = 0;
      for (int w2=0; w2<w; ++w2){ eqWP += eqc[q][w2]; gtWP += gtc[q][w2]; }
      const int eqBefore = eqPfx + eqWP + __popcll(beq[q] & lmask);
      const int gtBefore = gtPfx + gtWP + __popcll(bgt[q] & lmask);
      if (vb[q] > kth){
        const int pos = gtBefore + min(eqBefore, need_eq);
        if (pos < KLM) idxl_g[b*KLM + pos] = q*256 + t;
      } else if (vb[q] == kth && eqBefore < need_eq){
        const int pos = gtBefore + eqBefore;
        if (pos < KLM) idxl_g[b*KLM + pos] = q*256 + t;
      }
      eqPfx += eqc[q][0]+eqc[q][1]+eqc[q][2]+eqc[q][3];
      gtPfx += gtc[q][0]+gtc[q][1]+gtc[q][2]+gtc[q][3];
    }
  } else {
    // ---- convw ----
    const int i = (blk - 516)*256 + t;
    if (i < NL*DM*2*DI){
      const int col = i & 511;
      const int klin = i >> 9;
      const int l = klin >> 7, k = klin & 127;
      Wip[(((size_t)(l*64 + (k>>1))*512 + col) << 1) + (k & 1)] = __float2half_rn(inW[i]);
    }
    if (i < NL*DI*DM){
      const int c = i & (DM-1);
      const int klin = i >> 7;
      const int l = klin >> 8, k = klin & 255;
      Wop[(((size_t)(l*128 + (k>>1))*DM + c) << 1) + (k & 1)] = __float2half_rn(outW[i]);
    }
  }
}

// ---------------- fused pre: LN -> in_proj(fdot2) -> silu -> x_proj -> B/C/dt/lam ----------------
__global__ __launch_bounds__(256) void pre_kernel(
    const float* __restrict__ hb,
    const __half* __restrict__ Wip, const float* __restrict__ Wx,
    const float* __restrict__ Wdt, const float* __restrict__ bdt,
    const float* __restrict__ Bb, const float* __restrict__ Cb,
    const float* __restrict__ Bnw, const float* __restrict__ Cnw,
    const float* __restrict__ lnw, const float* __restrict__ lnb,
    __half* __restrict__ xph, __half* __restrict__ zsh,
    float* __restrict__ dtin, float* __restrict__ Shalf,
    float* __restrict__ Bmb, float* __restrict__ Cmb,
    float* __restrict__ lamb, float* __restrict__ mdtb)
{
  __shared__ __half2 xinh[NROWS][64+2];
  __shared__ float xps[NROWS][DI+4];
  __shared__ float spl[NROWS][40];
  __shared__ float pr[NROWS][4];

  const int t = threadIdx.x;
  const size_t R0 = (size_t)blockIdx.x * NROWS;

  { // LayerNorm: 32 threads per row; write half2 pairs
    const int r = t >> 5, j = t & 31;
    const float4 v = ((const float4*)(hb + (R0 + r)*DM))[j];
    float s = v.x+v.y+v.z+v.w;
    #pragma unroll
    for (int o=16;o>0;o>>=1) s += __shfl_xor(s,o,32);
    const float m = s*(1.0f/DM);
    const float dx=v.x-m, dy=v.y-m, dz=v.z-m, dw=v.w-m;
    float ss = dx*dx+dy*dy+dz*dz+dw*dw;
    #pragma unroll
    for (int o=16;o>0;o>>=1) ss += __shfl_xor(ss,o,32);
    const float inv = 1.0f/sqrtf(ss*(1.0f/DM) + 1e-5f);
    const int c = j*4;
    const float v0 = dx*inv*lnw[c+0] + lnb[c+0];
    const float v1 = dy*inv*lnw[c+1] + lnb[c+1];
    const float v2 = dz*inv*lnw[c+2] + lnb[c+2];
    const float v3 = dw*inv*lnw[c+3] + lnb[c+3];
    xinh[r][2*j]   = __halves2half2(__float2half_rn(v0), __float2half_rn(v1));
    xinh[r][2*j+1] = __halves2half2(__float2half_rn(v2), __float2half_rn(v3));
  }
  __syncthreads();

  { // xz = xin @ Wi via fdot2; thread t owns cols 2t,2t+1
    float2 a[NROWS];
    #pragma unroll
    for (int r=0;r<NROWS;r++){ a[r].x=0.0f; a[r].y=0.0f; }
    const __half2* Wc = (const __half2*)Wip + 2*t;
    #pragma unroll 4
    for (int p=0;p<64;p++){
      const float2 wv = *(const float2*)&Wc[(size_t)p*512];
      const __half2 w0 = *(const __half2*)&wv.x;
      const __half2 w1 = *(const __half2*)&wv.y;
      #pragma unroll
      for (int r=0;r<NROWS;r++){
        const __half2 xv = xinh[r][p];
        a[r].x = fdot2_(xv, w0, a[r].x);
        a[r].y = fdot2_(xv, w1, a[r].y);
      }
    }
    if (t < 128){
      #pragma unroll
      for (int r=0;r<NROWS;r++){
        const float sx = siluf_(a[r].x), sy = siluf_(a[r].y);
        xps[r][2*t] = sx; xps[r][2*t+1] = sy;
        *(__half2*)&xph[(R0+r)*DI + 2*t] =
            __halves2half2(__float2half_rn(sx), __float2half_rn(sy));
      }
    } else {
      const int zc = 2*t - 2*DI + DI;
      #pragma unroll
      for (int r=0;r<NROWS;r++){
        const float sx = siluf_(a[r].x), sy = siluf_(a[r].y);
        *(__half2*)&zsh[(R0+r)*DI + zc] =
            __halves2half2(__float2half_rn(sx), __float2half_rn(sy));
      }
    }
  }
  __syncthreads();

  // sp = xp @ Wx.  136 tasks = 8 rows x 17 col-pairs
  if (t < 136){
    const int r = t & 7, op = t >> 3;
    float ax=0.0f, ay=0.0f;
    for (int k=0;k<DI;k+=4){
      const float4 xv = *(const float4*)&xps[r][k];
      const float2 w0 = *(const float2*)&Wx[(size_t)(k+0)*34 + 2*op];
      const float2 w1 = *(const float2*)&Wx[(size_t)(k+1)*34 + 2*op];
      const float2 w2 = *(const float2*)&Wx[(size_t)(k+2)*34 + 2*op];
      const float2 w3 = *(const float2*)&Wx[(size_t)(k+3)*34 + 2*op];
      ax = fmaf(xv.x,w0.x,ax); ay = fmaf(xv.x,w0.y,ay);
      ax = fmaf(xv.y,w1.x,ax); ay = fmaf(xv.y,w1.y,ay);
      ax = fmaf(xv.z,w2.x,ax); ay = fmaf(xv.z,w2.y,ay);
      ax = fmaf(xv.w,w3.x,ax); ay = fmaf(xv.w,w3.y,ay);
    }
    spl[r][2*op] = ax; spl[r][2*op+1] = ay;
  }
  __syncthreads();

  { // B/C rms-norm: 256 tasks = 2 halves x 8 rows x 16 states
    const int half = t >> 7;
    const int r2 = (t >> 4) & 7, s2 = t & 15;
    const float* bias = half ? Cb : Bb;
    const float* wn   = half ? Cnw : Bnw;
    const float v = spl[r2][half*DS + s2] + bias[s2];
    float ss = v*v;
    #pragma unroll
    for (int o=8;o>0;o>>=1) ss += __shfl_xor(ss,o,16);
    const float inv = 1.0f/sqrtf(ss*(1.0f/DS) + 1.1920929e-07f);
    (half ? Cmb : Bmb)[(R0+r2)*DS + s2] = v*inv*wn[s2];
  }

  { // dt: thread = d; loop 8 rows; accumulate half-chunk sum
    const int lane = t & 63, w = t >> 6;
    const float wdt = Wdt[t], bdtv = bdt[t];
    float Sd = 0.0f;
    #pragma unroll
    for (int r=0;r<NROWS;r++){
      const float dval = softplusf_(fmaf(spl[r][32], wdt, bdtv));
      Sd += dval;
      float s = dval;
      #pragma unroll
      for (int o=32;o>0;o>>=1) s += __shfl_xor(s,o,64);
      if (lane==0) pr[r][w] = s;
    }
    Shalf[(size_t)blockIdx.x * DI + t] = Sd;
    if (t < NROWS){
      lamb[R0+t] = sigmoidf_(spl[t][33]);
      dtin[R0+t] = spl[t][32];
    }
  }
  __syncthreads();
  if (t < NROWS)
    mdtb[R0+t] = (pr[t][0]+pr[t][1]+pr[t][2]+pr[t][3])*(1.0f/DI);
}

// ---------------- scan phase 1 (inline prefix + rotation sincos) ----------------
__global__ __launch_bounds__(512) void scan1_kernel(
    const __half* __restrict__ xph, const float* __restrict__ dtin,
    const float* __restrict__ Wdt, const float* __restrict__ bdt,
    const float* __restrict__ Bmb, const float* __restrict__ lamb,
    const float* __restrict__ mdtb, const float* __restrict__ rf,
    const float* __restrict__ Alog, float* __restrict__ hend)
{
  __shared__ float Bst[TC+1][DS];
  __shared__ float lst[TC];
  __shared__ float dsl[TC];
  __shared__ double fqs[8];
  __shared__ double wred[8];
  __shared__ double mloc[16];
  __shared__ __half xpl[TC+1][DI+8];
  const int t = threadIdx.x;
  const int d  = t >> 1;
  const int s0 = (t & 1) * 8;
  const int c = blockIdx.x & (NC-1);
  const int b = blockIdx.x >> 7;
  const size_t bL = (size_t)b*SEQL;
  const int t0 = c*TC;
  const int id = blockIdx.x*256 + d;

  if (t < 8){
    const double xfr = (double)rf[t];
    fqs[t] = fmax(xfr, 0.0) + log1p(exp(-fabs(xfr)));
  }
  { // prefix partial: sum mdtb[0..t0-1] in f64
    double s = 0.0;
    const int i0 = t*4;
    #pragma unroll
    for (int q=0;q<4;q++){
      const int idx = i0+q;
      s += (idx < t0) ? (double)mdtb[bL + idx] : 0.0;
    }
    #pragma unroll
    for (int o=32;o>0;o>>=1) s += __shfl_down(s,o,64);
    if ((t&63)==0) wred[t>>6] = s;
  }
  if (t >= 64 && t < 80) mloc[t-64] = (double)mdtb[bL + t0 + (t-64)];
  for (int e=t; e<(TC+1)*DS; e+=512){
    const int j = e >> 4, s = e & 15;
    const int trow = t0 - 1 + j;
    Bst[j][s] = (trow >= 0) ? Bmb[(bL + trow)*DS + s] : 0.0f;
  }
  for (int e=t; e<(TC+1)*DI; e+=512){
    const int j = e >> 8, dd = e & (DI-1);
    const int trow = t0 - 1 + j;
    xpl[j][dd] = (trow >= 0) ? xph[(bL + trow)*DI + dd] : __float2half_rn(0.0f);
  }
  if (t < TC){
    lst[t] = lamb[bL + t0 + t];
    dsl[t] = dtin[bL + t0 + t];
  }
  __syncthreads();
  if (t < 136){
    const int j = t >> 3, f = t & 7;
    const int trow = t0 - 1 + j;
    if (trow >= 0){
      double cs = wred[0]+wred[1]+wred[2]+wred[3]+wred[4]+wred[5]+wred[6]+wred[7];
      for (int i=0;i<j;i++) cs += mloc[i];
      const double ang = cs * fqs[f];
      const double red = ang - floor(ang*0.15915494309189535)*6.283185307179586;
      float sa, ca;
      __sincosf((float)red, &sa, &ca);
      const float e0 = Bst[j][2*f], o0 = Bst[j][2*f+1];
      Bst[j][2*f]   = e0*ca - o0*sa;
      Bst[j][2*f+1] = e0*sa + o0*ca;
    }
  }
  __syncthreads();

  float A[8];
  #pragma unroll
  for (int s=0;s<8;s++) A[s] = fminf(-__expf(Alog[d*DS + s0 + s]), -1e-4f);
  const float wdt = Wdt[d], bdtv = bdt[d];
  float h[8], Bprev[8];
  #pragma unroll
  for (int s=0;s<8;s++) h[s]=0.0f;
  float xpm1;
  int tstart;
  if (t0 > 0){
    #pragma unroll
    for (int s=0;s<8;s++) Bprev[s] = Bst[0][s0+s];
    xpm1 = __half2float(xpl[0][d]);
    tstart = 0;
  } else {
    const float dtv = softplusf_(fmaf(dsl[0], wdt, bdtv));
    const float xpv = __half2float(xpl[1][d]);
    #pragma unroll
    for (int s=0;s<8;s++){
      h[s] = dtv*(Bst[1][s0+s]*xpv);
      Bprev[s] = Bst[1][s0+s];
    }
    xpm1 = xpv;
    tstart = 1;
  }
  for (int j=tstart; j<TC; ++j){
    const float dtv = softplusf_(fmaf(dsl[j], wdt, bdtv));
    const float xpv = __half2float(xpl[j+1][d]);
    const float lamv = lst[j];
    const float dl = dtv*lamv;
    const float dml = dtv - dl;
    #pragma unroll
    for (int s=0;s<8;s++){
      const float a = __expf(A[s]*dtv);
      const float Bc = Bst[j+1][s0+s];
      const float u = fmaf(dml*a, Bprev[s]*xpm1, dl*(Bc*xpv));
      h[s] = fmaf(a, h[s], u);
      Bprev[s] = Bc;
    }
    xpm1 = xpv;
  }
  store8(hend + (size_t)id*DS + s0, h);
}

// ---------------- scan phase 2: parallel Kogge-Stone over chunks; P = exp(A*S) ----------------
__global__ __launch_bounds__(128) void scan2_kernel(
    float* __restrict__ hend, const float* __restrict__ Shalf,
    const float* __restrict__ Alog)
{
  __shared__ float hS[NC][DS+1];
  __shared__ float pS[NC][DS+1];
  const int c = threadIdx.x;
  const int d = blockIdx.x & (DI-1);
  const int b = blockIdx.x >> 8;
  const float S = Shalf[(size_t)(b*(SEQL/NROWS) + 2*c)*DI + d]
                + Shalf[(size_t)(b*(SEQL/NROWS) + 2*c + 1)*DI + d];
  float P[DS], h[DS];
  #pragma unroll
  for (int s=0;s<DS;s++){
    const float A = fminf(-__expf(Alog[d*DS+s]), -1e-4f);
    P[s] = __expf(A*S);
  }
  load16(hend + (((size_t)(b*NC + c))*DI + d)*DS, h);
  #pragma unroll
  for (int s=0;s<DS;s++){ hS[c][s]=h[s]; pS[c][s]=P[s]; }
  __syncthreads();
  for (int off=1; off<NC; off<<=1){
    float hn[DS], pn[DS];
    const int src = c - off;
    if (src >= 0){
      #pragma unroll
      for (int s=0;s<DS;s++){ hn[s]=hS[src][s]; pn[s]=pS[src][s]; }
    }
    __syncthreads();
    if (src >= 0){
      #pragma unroll
      for (int s=0;s<DS;s++){
        h[s] = fmaf(P[s], hn[s], h[s]);
        P[s] *= pn[s];
        hS[c][s] = h[s]; pS[c][s] = P[s];
      }
    }
    __syncthreads();
  }
  float o[DS];
  if (c == 0){
    #pragma unroll
    for (int s=0;s<DS;s++) o[s] = 0.0f;
  } else {
    #pragma unroll
    for (int s=0;s<DS;s++) o[s] = hS[c-1][s];
  }
  store16(hend + (((size_t)(b*NC + c))*DI + d)*DS, o);
}

// ---------------- scan phase 3 + fdot2 out_proj + residual (inline prefix) ----------------
__global__ __launch_bounds__(512) void scan3post_kernel(
    const __half* __restrict__ xph, const float* __restrict__ dtin,
    const float* __restrict__ Wdt, const float* __restrict__ bdt,
    const float* __restrict__ Bmb, const float* __restrict__ Cmb,
    const float* __restrict__ lamb, const __half* __restrict__ zsh,
    const float* __restrict__ mdtb, const float* __restrict__ rf,
    const float* __restrict__ Alog, const float* __restrict__ Dv,
    const float* __restrict__ Hin, const __half* __restrict__ Wop,
    float* __restrict__ hb)
{
  __shared__ float Bst[TC+1][DS];
  __shared__ float Cst[TC][DS];
  __shared__ float lst[TC];
  __shared__ float dsl[TC];
  __shared__ double fqs[8];
  __shared__ double wred[8];
  __shared__ double mloc[16];
  __shared__ __half xpl[TC+1][DI+8];
  __shared__ __half zsl[TC][DI+8];
  __shared__ __half ysh[TC][DI+8];
  __shared__ float red[TC][132];
  const int t = threadIdx.x;
  const int d  = t >> 1;
  const int sh = t & 1;
  const int s0 = sh * 8;
  const int c = blockIdx.x & (NC-1);
  const int b = blockIdx.x >> 7;
  const size_t bL = (size_t)b*SEQL;
  const int t0 = c*TC;
  const int id = blockIdx.x*256 + d;

  if (t < 8){
    const double xfr = (double)rf[t];
    fqs[t] = fmax(xfr, 0.0) + log1p(exp(-fabs(xfr)));
  }
  { // prefix partial
    double s = 0.0;
    const int i0 = t*4;
    #pragma unroll
    for (int q=0;q<4;q++){
      const int idx = i0+q;
      s += (idx < t0) ? (double)mdtb[bL + idx] : 0.0;
    }
    #pragma unroll
    for (int o=32;o>0;o>>=1) s += __shfl_down(s,o,64);
    if ((t&63)==0) wred[t>>6] = s;
  }
  if (t >= 64 && t < 80) mloc[t-64] = (double)mdtb[bL + t0 + (t-64)];
  for (int e=t; e<(TC+1)*DS; e+=512){
    const int j = e >> 4, s = e & 15;
    const int trow = t0 - 1 + j;
    Bst[j][s] = (trow >= 0) ? Bmb[(bL + trow)*DS + s] : 0.0f;
    if (j < TC) Cst[j][s] = Cmb[(bL + t0 + j)*DS + s];
  }
  for (int e=t; e<(TC+1)*DI; e+=512){
    const int j = e >> 8, dd = e & (DI-1);
    const int trow = t0 - 1 + j;
    xpl[j][dd] = (trow >= 0) ? xph[(bL + trow)*DI + dd] : __float2half_rn(0.0f);
    if (j < TC) zsl[j][dd] = zsh[(bL + t0 + j)*DI + dd];
  }
  if (t < TC){
    lst[t] = lamb[bL + t0 + t];
    dsl[t] = dtin[bL + t0 + t];
  }
  __syncthreads();
  if (t < 264){
    const double base = wred[0]+wred[1]+wred[2]+wred[3]+wred[4]+wred[5]+wred[6]+wred[7];
    if (t < 136){
      const int j = t >> 3, f = t & 7;
      const int trow = t0 - 1 + j;
      if (trow >= 0){
        double cs = base;
        for (int i=0;i<j;i++) cs += mloc[i];
        const double ang = cs * fqs[f];
        const double rd = ang - floor(ang*0.15915494309189535)*6.283185307179586;
        float sa, ca;
        __sincosf((float)rd, &sa, &ca);
        const float e0 = Bst[j][2*f], o0 = Bst[j][2*f+1];
        Bst[j][2*f]   = e0*ca - o0*sa;
        Bst[j][2*f+1] = e0*sa + o0*ca;
      }
    } else {
      const int e2 = t - 136;
      const int j = e2 >> 3, f = e2 & 7;
      double cs = base;
      for (int i=0;i<=j;i++) cs += mloc[i];
      const double ang = cs * fqs[f];
      const double rd = ang - floor(ang*0.15915494309189535)*6.283185307179586;
      float sa, ca;
      __sincosf((float)rd, &sa, &ca);
      const float e0 = Cst[j][2*f], o0 = Cst[j][2*f+1];
      Cst[j][2*f]   = e0*ca - o0*sa;
      Cst[j][2*f+1] = e0*sa + o0*ca;
    }
  }
  __syncthreads();

  float A[8];
  #pragma unroll
  for (int s=0;s<8;s++) A[s] = fminf(-__expf(Alog[d*DS + s0 + s]), -1e-4f);
  const float wdt = Wdt[d], bdtv = bdt[d];
  const float dvp = Dv[d];
  float h[8], Bprev[8];
  load8(Hin + (size_t)id*DS + s0, h);
  float xpm1;
  int tstart;
  if (t0 > 0){
    #pragma unroll
    for (int s=0;s<8;s++) Bprev[s] = Bst[0][s0+s];
    xpm1 = __half2float(xpl[0][d]);
    tstart = 0;
  } else {
    const float dtv = softplusf_(fmaf(dsl[0], wdt, bdtv));
    const float xpv = __half2float(xpl[1][d]);
    float y = 0.0f;
    #pragma unroll
    for (int s=0;s<8;s++){
      h[s] = dtv*(Bst[1][s0+s]*xpv);
      y = fmaf(h[s], Cst[0][s0+s], y);
      Bprev[s] = Bst[1][s0+s];
    }
    const float ytot = y + __shfl_xor(y, 1, 64);
    if (sh == 0) ysh[0][d] = __float2half_rn((ytot + xpv*dvp)*__half2float(zsl[0][d]));
    xpm1 = xpv;
    tstart = 1;
  }
  for (int j=tstart; j<TC; ++j){
    const float dtv = softplusf_(fmaf(dsl[j], wdt, bdtv));
    const float xpv = __half2float(xpl[j+1][d]);
    const float lamv = lst[j];
    const float dl = dtv*lamv;
    const float dml = dtv - dl;
    float y = 0.0f;
    #pragma unroll
    for (int s=0;s<8;s++){
      const float a = __expf(A[s]*dtv);
      const float Bc = Bst[j+1][s0+s];
      const float u = fmaf(dml*a, Bprev[s]*xpm1, dl*(Bc*xpv));
      h[s] = fmaf(a, h[s], u);
      y = fmaf(h[s], Cst[j][s0+s], y);
      Bprev[s] = Bc;
    }
    const float ytot = y + __shfl_xor(y, 1, 64);
    if (sh == 0) ysh[j][d] = __float2half_rn((ytot + xpv*dvp)*__half2float(zsl[j][d]));
    xpm1 = xpv;
  }
  __syncthreads();

  // ---- out_proj via fdot2 (k-pair packed Wo) + k-split + residual ----
  {
    const int cg2  = t & 31;          // col quad: cols 4cg2..4cg2+3
    const int ks2  = (t >> 5) & 1;    // k-seg low bit (within wave)
    const int rg   = (t >> 6) & 3;    // row quad
    const int ksHi = t >> 8;          // k-seg high bit (across waves)
    const int seg = ksHi*2 + ks2;
    const int k0p = seg*32;           // pair index base (32 pairs = 64 k)
    const int c0c = cg2*4;
    const __half2* Wp = (const __half2*)Wop;
    float acc[4][4];
    #pragma unroll
    for (int rr=0;rr<4;rr++){ acc[rr][0]=0.f; acc[rr][1]=0.f; acc[rr][2]=0.f; acc[rr][3]=0.f; }
    for (int kp=k0p; kp<k0p+32; ++kp){
      const float2 wv0 = *(const float2*)&Wp[(size_t)kp*DM + c0c];
      const float2 wv1 = *(const float2*)&Wp[(size_t)kp*DM + c0c + 2];
      const __half2 wc0 = *(const __half2*)&wv0.x;
      const __half2 wc1 = *(const __half2*)&wv0.y;
      const __half2 wc2 = *(const __half2*)&wv1.x;
      const __half2 wc3 = *(const __half2*)&wv1.y;
      #pragma unroll
      for (int rr=0;rr<4;rr++){
        const __half2 yv = *(const __half2*)&ysh[rg*4+rr][2*kp];
        acc[rr][0] = fdot2_(yv, wc0, acc[rr][0]);
        acc[rr][1] = fdot2_(yv, wc1, acc[rr][1]);
        acc[rr][2] = fdot2_(yv, wc2, acc[rr][2]);
        acc[rr][3] = fdot2_(yv, wc3, acc[rr][3]);
      }
    }
    // reduce ks2 within wave (lane +32)
    #pragma unroll
    for (int rr=0;rr<4;rr++){
      #pragma unroll
      for (int cc=0;cc<4;cc++) acc[rr][cc] += __shfl_down(acc[rr][cc], 32, 64);
    }
    __syncthreads();
    const int lane = t & 63;
    if (ksHi == 1 && lane < 32){
      #pragma unroll
      for (int rr=0;rr<4;rr++)
        *(float4*)&red[rg*4+rr][c0c] = make_float4(acc[rr][0],acc[rr][1],acc[rr][2],acc[rr][3]);
    }
    __syncthreads();
    if (ksHi == 0 && lane < 32){
      #pragma unroll
      for (int rr=0;rr<4;rr++){
        const float4 rv = *(const float4*)&red[rg*4+rr][c0c];
        const size_t row = bL + t0 + rg*4 + rr;
        float4 hv = *(const float4*)&hb[row*DM + c0c];
        hv.x += acc[rr][0] + rv.x; hv.y += acc[rr][1] + rv.y;
        hv.z += acc[rr][2] + rv.z; hv.w += acc[rr][3] + rv.w;
        *(float4*)&hb[row*DM + c0c] = hv;
      }
    }
  }
}

// ---------------- final attention: 4 blocks, all heads share kv; inline LN + out proj ----------------
__global__ __launch_bounds__(256) void attn_kernel(
    const float* __restrict__ hb, const float* __restrict__ sk,
    const int* __restrict__ idxl_g,
    const float* __restrict__ fnw, const float* __restrict__ fnb,
    const float* __restrict__ WQ, const float* __restrict__ bQ,
    const float* __restrict__ WK, const float* __restrict__ bK,
    const float* __restrict__ WV, const float* __restrict__ bV,
    const float* __restrict__ WO, const float* __restrict__ bO,
    float* __restrict__ outp)
{
  __shared__ float kv[KLM][DM+4];
  __shared__ float mo[DM];
  __shared__ float Qs[DM];
  __shared__ float qk[NHEAD][DM];
  __shared__ float bterm[NHEAD];
  __shared__ float sc[NHEAD][KLM];
  __shared__ float pbar[NHEAD][DM];
  __shared__ float attno[DM];
  const int b = blockIdx.x;
  const int t = threadIdx.x;
  const int lane = t & 63, w = t >> 6;

  if (t < 64){
    const float* hr = hb + ((size_t)b*SEQL + (SEQL-1))*DM;
    const float v0 = hr[t], v1 = hr[t+64];
    float s = v0+v1;
    #pragma unroll
    for (int o=32;o>0;o>>=1) s += __shfl_xor(s,o,64);
    const float m = s*(1.0f/DM);
    const float d0=v0-m, d1=v1-m;
    float ss = d0*d0 + d1*d1;
    #pragma unroll
    for (int o=32;o>0;o>>=1) ss += __shfl_xor(ss,o,64);
    const float inv = 1.0f/sqrtf(ss*(1.0f/DM) + 1e-5f);
    mo[t]    = d0*inv*fnw[t]    + fnb[t];
    mo[t+64] = d1*inv*fnw[t+64] + fnb[t+64];
  }
  for (int e=t; e<KLM*DM; e+=256){
    const int j = e >> 7, cc = e & (DM-1);
    kv[j][cc] = sk[((size_t)b*SEQL + idxl_g[b*KLM + j])*DM + cc];
  }
  __syncthreads();

  if (t < DM){
    float a = bQ[t];
    #pragma unroll 4
    for (int k=0;k<DM;k++) a = fmaf(mo[k], WQ[(size_t)k*DM + t], a);
    Qs[t] = a;
  }
  __syncthreads();
  for (int e=t; e<NHEAD*DM; e+=256){
    const int hh = e >> 7, m = e & (DM-1);
    const int c0 = hh*DHEAD;
    float a = 0.0f;
    #pragma unroll
    for (int cc=0; cc<DHEAD; cc++) a = fmaf(WK[(size_t)m*DM + c0 + cc], Qs[c0+cc], a);
    qk[hh][m] = a;
  }
  if (t < NHEAD){
    float a = 0.0f;
    for (int cc=0; cc<DHEAD; cc++) a += bK[t*DHEAD+cc]*Qs[t*DHEAD+cc];
    bterm[t] = a;
  }
  __syncthreads();
  for (int e=t; e<NHEAD*KLM; e+=256){
    const int hh = e/KLM, j = e - hh*KLM;
    float a = bterm[hh];
    for (int m=0;m<DM;m+=4){
      const float4 kvv = *(const float4*)&kv[j][m];
      const float4 qv  = *(const float4*)&qk[hh][m];
      a = fmaf(kvv.x,qv.x,a); a = fmaf(kvv.y,qv.y,a);
      a = fmaf(kvv.z,qv.z,a); a = fmaf(kvv.w,qv.w,a);
    }
    sc[hh][j] = a*0.17677669529663687f;
  }
  __syncthreads();
  { // softmax per head: wave w handles head w
    const int hh = w;
    const float v0 = (lane < KLM) ? sc[hh][lane] : -3.0e38f;
    const float v1 = (lane+64 < KLM) ? sc[hh][lane+64] : -3.0e38f;
    float mx = fmaxf(v0, v1);
    #pragma unroll
    for (int o2=32;o2>0;o2>>=1) mx = fmaxf(mx, __shfl_xor(mx,o2,64));
    const float e0 = (lane < KLM) ? __expf(v0-mx) : 0.0f;
    const float e1 = (lane+64 < KLM) ? __expf(v1-mx) : 0.0f;
    float sm = e0+e1;
    #pragma unroll
    for (int o2=32;o2>0;o2>>=1) sm += __shfl_xor(sm,o2,64);
    const float inv2 = rcp_(sm);
    if (lane < KLM) sc[hh][lane] = e0*inv2;
    if (lane+64 < KLM) sc[hh][lane+64] = e1*inv2;
  }
  __syncthreads();
  for (int e=t; e<NHEAD*DM; e+=256){
    const int hh = e >> 7, m = e & (DM-1);
    float a = 0.0f;
    #pragma unroll 4
    for (int j=0;j<KLM;j++) a = fmaf(sc[hh][j], kv[j][m], a);
    pbar[hh][m] = a;
  }
  __syncthreads();
  if (t < DM){
    const int hh = t >> 5;
    float a = bV[t];
    for (int m=0;m<DM;m+=4){
      const float4 pv = *(const float4*)&pbar[hh][m];
      a = fmaf(pv.x, WV[(size_t)(m+0)*DM + t], a);
      a = fmaf(pv.y, WV[(size_t)(m+1)*DM + t], a);
      a = fmaf(pv.z, WV[(size_t)(m+2)*DM + t], a);
      a = fmaf(pv.w, WV[(size_t)(m+3)*DM + t], a);
    }
    attno[t] = a;
  }
  __syncthreads();
  if (t < DM){
    float a = bO[t];
    #pragma unroll 4
    for (int c2=0;c2<DM;c2++) a = fmaf(attno[c2], WO[(size_t)c2*DM + t], a);
    outp[(size_t)b*DM + t] = a;
  }
}

extern "C" void kernel_launch(void* const* d_in, const int* in_sizes, int n_in,
                              void* d_out, int out_size, void* d_ws, size_t ws_size,
                              hipStream_t stream)
{
  (void)in_sizes; (void)n_in; (void)out_size; (void)ws_size;
  const float* x    = (const float*)d_in[0];
  const float* hw   = (const float*)d_in[1];
  const float* embW = (const float*)d_in[2];
  const float* embB = (const float*)d_in[3];
  const float* skW  = (const float*)d_in[4];
  const float* skB  = (const float*)d_in[5];
  const float* inW  = (const float*)d_in[6];
  const float* xpW  = (const float*)d_in[7];
  const float* dtW  = (const float*)d_in[8];
  const float* dtB  = (const float*)d_in[9];
  const float* Alog = (const float*)d_in[10];
  const float* Bb   = (const float*)d_in[11];
  const float* Cb   = (const float*)d_in[12];
  const float* Bnw  = (const float*)d_in[13];
  const float* Cnw  = (const float*)d_in[14];
  const float* rf   = (const float*)d_in[15];
  const float* Dpar = (const float*)d_in[16];
  const float* outW = (const float*)d_in[17];
  const float* lnW  = (const float*)d_in[18];
  const float* lnB  = (const float*)d_in[19];
  const float* fnW  = (const float*)d_in[20];
  const float* fnB  = (const float*)d_in[21];
  const float* WQ = (const float*)d_in[22]; const float* bQ = (const float*)d_in[23];
  const float* WK = (const float*)d_in[24]; const float* bK = (const float*)d_in[25];
  const float* WV = (const float*)d_in[26]; const float* bV = (const float*)d_in[27];
  const float* WO = (const float*)d_in[28]; const float* bO = (const float*)d_in[29];

  float* ws = (float*)d_ws;
  size_t off = 0;
  float* hb    = ws + off; off += (size_t)BSZ*SEQL*DM;
  float* sk    = ws + off; off += (size_t)BSZ*SEQL*DM;
  __half* xph  = (__half*)(ws + off); off += (size_t)BSZ*SEQL*DI/2;
  __half* zsh  = (__half*)(ws + off); off += (size_t)BSZ*SEQL*DI/2;
  float* Bmb   = ws + off; off += (size_t)BSZ*SEQL*DS;
  float* Cmb   = ws + off; off += (size_t)BSZ*SEQL*DS;
  float* lamb  = ws + off; off += (size_t)BSZ*SEQL;
  float* mdtb  = ws + off; off += (size_t)BSZ*SEQL;
  float* dtin  = ws + off; off += (size_t)BSZ*SEQL;
  float* Shalf = ws + off; off += (size_t)BSZ*(SEQL/NROWS)*DI;
  float* hend  = ws + off; off += (size_t)BSZ*NC*DI*DS;
  int* idxl_g  = (int*)(ws + off); off += (size_t)BSZ*KLM;
  __half* Wip  = (__half*)(ws + off); off += (size_t)NL*DM*2*DI/2;
  __half* Wop  = (__half*)(ws + off); off += (size_t)NL*DI*DM/2;

  prologue_kernel<<<516 + (NL*DM*2*DI + 255)/256, 256, 0, stream>>>(
      x, hw, embW, embB, skW, skB, hb, sk, inW, outW, Wip, Wop, idxl_g);

  for (int i=0;i<NL;i++){
    pre_kernel<<<BSZ*SEQL/NROWS, 256, 0, stream>>>(hb,
        Wip + (size_t)i*DM*2*DI, xpW + (size_t)i*DI*34,
        dtW + (size_t)i*DI, dtB + (size_t)i*DI,
        Bb + i*DS, Cb + i*DS, Bnw + i*DS, Cnw + i*DS,
        lnW + i*DM, lnB + i*DM,
        xph, zsh, dtin, Shalf, Bmb, Cmb, lamb, mdtb);
    scan1_kernel<<<BSZ*NC, 512, 0, stream>>>(xph, dtin,
        dtW + (size_t)i*DI, dtB + (size_t)i*DI,
        Bmb, lamb, mdtb, rf + i*8, Alog + (size_t)i*DI*DS, hend);
    scan2_kernel<<<BSZ*DI, 128, 0, stream>>>(hend, Shalf, Alog + (size_t)i*DI*DS);
    scan3post_kernel<<<BSZ*NC, 512, 0, stream>>>(xph, dtin,
        dtW + (size_t)i*DI, dtB + (size_t)i*DI,
        Bmb, Cmb, lamb, zsh, mdtb, rf + i*8,
        Alog + (size_t)i*DI*DS, Dpar + (size_t)i*DI, hend,
        Wop + (size_t)i*DI*DM, hb);
  }

  attn_kernel<<<BSZ, 256, 0, stream>>>(hb, sk, idxl_g, fnW, fnB,
      WQ, bQ, WK, bK, WV, bV, WO, bO, (float*)d_out);
}